// Round 2
// baseline (192.606 us; speedup 1.0000x reference)
//
#include <hip/hip_runtime.h>
#include <stdint.h>

typedef float  f32x4 __attribute__((ext_vector_type(4)));
typedef short  s16x8 __attribute__((ext_vector_type(8)));
typedef unsigned int u32;
typedef unsigned short u16;
typedef unsigned int u32x4 __attribute__((ext_vector_type(4)));

#define HID 768
#define OUTF 128
#define LQ 32
#define LD 256
#define BD 512
#define NKK 24   // 768/32

// pack two f32 -> two bf16 (round-to-nearest, ties away): 2 adds + 1 v_perm
__device__ __forceinline__ u32 pk_rna(float lo, float hi) {
    u32 a = __builtin_bit_cast(u32, lo) + 0x8000u;
    u32 b = __builtin_bit_cast(u32, hi) + 0x8000u;
    return __builtin_amdgcn_perm(b, a, 0x07060302u);  // {b.hi16, a.hi16}
}

__device__ __forceinline__ s16x8 cvt8(f32x4 lo, f32x4 hi) {
    u32x4 p;
    p[0] = pk_rna(lo[0], lo[1]);
    p[1] = pk_rna(lo[2], lo[3]);
    p[2] = pk_rna(hi[0], hi[1]);
    p[3] = pk_rna(hi[2], hi[3]);
    return __builtin_bit_cast(s16x8, p);
}

__device__ __forceinline__ u16 f2bf(float x) {
    return (u16)((__builtin_bit_cast(u32, x) + 0x8000u) >> 16);
}

// ---------------- kernel 0: W f32 -> bf16, MFMA-fragment layout ----------------
// Wb2 bf16-unit index: ((((kk*4+g)*16+l15)*8+cf)*8 + j)  <=>  W[f=cf*16+l15][k=kk*32+g*8+j]
// One dword t holds j = 2*(t&3), 2*(t&3)+1.
__global__ __launch_bounds__(256) void wconv(const float* __restrict__ W,
                                             u32* __restrict__ Wb2) {
    int t = blockIdx.x * 256 + threadIdx.x;   // 0..49151
    int j2  = t & 3;
    int cf  = (t >> 2) & 7;
    int l15 = (t >> 5) & 15;
    int g   = (t >> 9) & 3;
    int kk  = t >> 11;
    int f = cf * 16 + l15;
    int k = kk * 32 + g * 8 + j2 * 2;
    const float* src = W + (size_t)f * HID + k;
    Wb2[t] = pk_rna(src[0], src[1]);
}

// ---------------- kernel 1: Q projection + L2 norm -> bf16 ----------------
// grid = 64, block = 256 (4 waves; wave w owns cols [32w,32w+32) => cf = 2w, 2w+1)
__global__ __launch_bounds__(256) void qproj(const float* __restrict__ qh,
                                             const u16* __restrict__ Wb2,
                                             u16* __restrict__ Qb) {
    const int b = blockIdx.x;
    const int tid = threadIdx.x;
    const int w = tid >> 6, lane = tid & 63, g = lane >> 4, l15 = lane & 15;

    f32x4 acc[2][2] = {};
    const float* A0 = qh + ((size_t)b * LQ + l15) * HID + g * 8;
    const float* A1 = A0 + 16 * HID;
    const u16* Bp = Wb2 + (size_t)(g * 16 + l15) * 64 + w * 16;

    for (int kk = 0; kk < NKK; ++kk) {
        f32x4 x0 = *(const f32x4*)A0;
        f32x4 x1 = *(const f32x4*)(A0 + 4);
        f32x4 y0 = *(const f32x4*)A1;
        f32x4 y1 = *(const f32x4*)(A1 + 4);
        s16x8 b0 = *(const s16x8*)(Bp);
        s16x8 b1 = *(const s16x8*)(Bp + 8);
        s16x8 a0 = cvt8(x0, x1);
        s16x8 a1 = cvt8(y0, y1);
        acc[0][0] = __builtin_amdgcn_mfma_f32_16x16x32_bf16(a0, b0, acc[0][0], 0, 0, 0);
        acc[0][1] = __builtin_amdgcn_mfma_f32_16x16x32_bf16(a0, b1, acc[0][1], 0, 0, 0);
        acc[1][0] = __builtin_amdgcn_mfma_f32_16x16x32_bf16(a1, b0, acc[1][0], 0, 0, 0);
        acc[1][1] = __builtin_amdgcn_mfma_f32_16x16x32_bf16(a1, b1, acc[1][1], 0, 0, 0);
        A0 += 32; A1 += 32; Bp += 4096;
    }

    __shared__ float part[4][32];
    __shared__ float invl[32];
#pragma unroll
    for (int rf = 0; rf < 2; ++rf)
#pragma unroll
        for (int reg = 0; reg < 4; ++reg) {
            float ss = acc[rf][0][reg] * acc[rf][0][reg] + acc[rf][1][reg] * acc[rf][1][reg];
            ss += __shfl_xor(ss, 1); ss += __shfl_xor(ss, 2);
            ss += __shfl_xor(ss, 4); ss += __shfl_xor(ss, 8);
            if (l15 == 0) part[w][rf * 16 + g * 4 + reg] = ss;
        }
    __syncthreads();
    if (tid < 32) {
        float ss = part[0][tid] + part[1][tid] + part[2][tid] + part[3][tid];
        invl[tid] = 1.f / fmaxf(sqrtf(ss), 1e-12f);
    }
    __syncthreads();
#pragma unroll
    for (int rf = 0; rf < 2; ++rf)
#pragma unroll
        for (int cf = 0; cf < 2; ++cf)
#pragma unroll
            for (int reg = 0; reg < 4; ++reg) {
                int q = rf * 16 + g * 4 + reg;
                int f = w * 32 + cf * 16 + l15;
                Qb[(size_t)b * LQ * OUTF + q * OUTF + f] = f2bf(acc[rf][cf][reg] * invl[q]);
            }
}

// ---------------- kernel 2: D projection + norm + mask + MaxSim ----------------
// grid = 512 (one doc), block = 512 (8 waves; wave w owns doc rows [32w,32w+32))
__global__ __launch_bounds__(512, 4) void dscore(const float* __restrict__ dh,
                                                 const int* __restrict__ ids,
                                                 const int* __restrict__ skiplist,
                                                 const u16* __restrict__ Wb2,
                                                 const u16* __restrict__ Qb,
                                                 float* __restrict__ out) {
    const int bd = blockIdx.x;
    const int tid = threadIdx.x;
    const int w = tid >> 6, lane = tid & 63, g = lane >> 4, l15 = lane & 15;

    __shared__ u16  Dls[8 * 32 * OUTF];   // 64 KB, XOR-swizzled rows
    __shared__ int  ms[LD];
    __shared__ int  sk[64];
    __shared__ float wm[8][32];

    // ----- mask -----
    if (tid < 64) sk[tid] = skiplist[tid];
    __syncthreads();
    if (tid < LD) {
        int id = ids[(size_t)bd * LD + tid];
        int keep = (id != 0);
#pragma unroll
        for (int j = 0; j < 64; ++j) keep &= (id != sk[j]);
        ms[tid] = keep;
    }

    // ----- projection GEMM: rows [32w,32w+32) x cols 128, K=768 -----
    f32x4 acc[2][8] = {};
    const int rowbase = w * 32;
    const float* A0 = dh + ((size_t)bd * LD + rowbase + l15) * HID + g * 8;
    const float* A1 = A0 + 16 * HID;
    const u16* Bp = Wb2 + (size_t)(g * 16 + l15) * 64;

    for (int kk = 0; kk < NKK; ++kk) {
        f32x4 x0 = *(const f32x4*)A0;
        f32x4 x1 = *(const f32x4*)(A0 + 4);
        f32x4 y0 = *(const f32x4*)A1;
        f32x4 y1 = *(const f32x4*)(A1 + 4);
        const s16x8* bp = (const s16x8*)Bp;
        s16x8 b0 = bp[0], b1 = bp[1], b2 = bp[2], b3 = bp[3];
        s16x8 a0 = cvt8(x0, x1);
        s16x8 a1 = cvt8(y0, y1);
        acc[0][0] = __builtin_amdgcn_mfma_f32_16x16x32_bf16(a0, b0, acc[0][0], 0, 0, 0);
        acc[1][0] = __builtin_amdgcn_mfma_f32_16x16x32_bf16(a1, b0, acc[1][0], 0, 0, 0);
        acc[0][1] = __builtin_amdgcn_mfma_f32_16x16x32_bf16(a0, b1, acc[0][1], 0, 0, 0);
        acc[1][1] = __builtin_amdgcn_mfma_f32_16x16x32_bf16(a1, b1, acc[1][1], 0, 0, 0);
        acc[0][2] = __builtin_amdgcn_mfma_f32_16x16x32_bf16(a0, b2, acc[0][2], 0, 0, 0);
        acc[1][2] = __builtin_amdgcn_mfma_f32_16x16x32_bf16(a1, b2, acc[1][2], 0, 0, 0);
        acc[0][3] = __builtin_amdgcn_mfma_f32_16x16x32_bf16(a0, b3, acc[0][3], 0, 0, 0);
        acc[1][3] = __builtin_amdgcn_mfma_f32_16x16x32_bf16(a1, b3, acc[1][3], 0, 0, 0);
        s16x8 b4 = bp[4], b5 = bp[5], b6 = bp[6], b7 = bp[7];
        acc[0][4] = __builtin_amdgcn_mfma_f32_16x16x32_bf16(a0, b4, acc[0][4], 0, 0, 0);
        acc[1][4] = __builtin_amdgcn_mfma_f32_16x16x32_bf16(a1, b4, acc[1][4], 0, 0, 0);
        acc[0][5] = __builtin_amdgcn_mfma_f32_16x16x32_bf16(a0, b5, acc[0][5], 0, 0, 0);
        acc[1][5] = __builtin_amdgcn_mfma_f32_16x16x32_bf16(a1, b5, acc[1][5], 0, 0, 0);
        acc[0][6] = __builtin_amdgcn_mfma_f32_16x16x32_bf16(a0, b6, acc[0][6], 0, 0, 0);
        acc[1][6] = __builtin_amdgcn_mfma_f32_16x16x32_bf16(a1, b6, acc[1][6], 0, 0, 0);
        acc[0][7] = __builtin_amdgcn_mfma_f32_16x16x32_bf16(a0, b7, acc[0][7], 0, 0, 0);
        acc[1][7] = __builtin_amdgcn_mfma_f32_16x16x32_bf16(a1, b7, acc[1][7], 0, 0, 0);
        A0 += 32; A1 += 32; Bp += 4096;
    }

    // ----- per-row L2 norm (cols spread over l15 groups) -----
    float inv[2][4];
#pragma unroll
    for (int rf = 0; rf < 2; ++rf)
#pragma unroll
        for (int reg = 0; reg < 4; ++reg) {
            float ss = 0.f;
#pragma unroll
            for (int cf = 0; cf < 8; ++cf) ss += acc[rf][cf][reg] * acc[rf][cf][reg];
            ss += __shfl_xor(ss, 1); ss += __shfl_xor(ss, 2);
            ss += __shfl_xor(ss, 4); ss += __shfl_xor(ss, 8);
            inv[rf][reg] = 1.f / fmaxf(sqrtf(ss), 1e-12f);
        }

    // ----- write normalized D (bf16) to swizzled LDS (own wave slice only) -----
#pragma unroll
    for (int rf = 0; rf < 2; ++rf)
#pragma unroll
        for (int cf = 0; cf < 8; ++cf)
#pragma unroll
            for (int reg = 0; reg < 4; ++reg) {
                int r = rowbase + rf * 16 + g * 4 + reg;   // 0..255 block-local
                int f = cf * 16 + l15;
                Dls[(r * OUTF + f) ^ ((r & 7) << 3)] = f2bf(acc[rf][cf][reg] * inv[rf][reg]);
            }

    // ----- sim = Q[b] (32 x K=128) x D_wave^T (32 rows), per-wave -----
    f32x4 acc2[2][2] = {};
    const u16* Qbb = Qb + (size_t)(bd >> 3) * LQ * OUTF;
    for (int k = 0; k < OUTF; k += 32) {
        s16x8 qa[2], db[2];
#pragma unroll
        for (int qf = 0; qf < 2; ++qf)
            qa[qf] = *(const s16x8*)(Qbb + (qf * 16 + l15) * OUTF + k + g * 8);
#pragma unroll
        for (int nf = 0; nf < 2; ++nf) {
            int r = rowbase + nf * 16 + l15;
            db[nf] = *(const s16x8*)&Dls[(r * OUTF + k + g * 8) ^ ((r & 7) << 3)];
        }
#pragma unroll
        for (int qf = 0; qf < 2; ++qf)
#pragma unroll
            for (int nf = 0; nf < 2; ++nf)
                acc2[qf][nf] = __builtin_amdgcn_mfma_f32_16x16x32_bf16(qa[qf], db[nf], acc2[qf][nf], 0, 0, 0);
    }

    __syncthreads();  // ms ready (written before GEMM) and wm buffer free

    // ----- masked max over this wave's 32 doc rows -----
    int k0m = ms[rowbase + l15];
    int k1m = ms[rowbase + 16 + l15];
#pragma unroll
    for (int qf = 0; qf < 2; ++qf)
#pragma unroll
        for (int reg = 0; reg < 4; ++reg) {
            float v0 = k0m ? acc2[qf][0][reg] : -INFINITY;
            float v1 = k1m ? acc2[qf][1][reg] : -INFINITY;
            float v = fmaxf(v0, v1);
            v = fmaxf(v, __shfl_xor(v, 1));
            v = fmaxf(v, __shfl_xor(v, 2));
            v = fmaxf(v, __shfl_xor(v, 4));
            v = fmaxf(v, __shfl_xor(v, 8));
            if (l15 == 0) wm[w][qf * 16 + g * 4 + reg] = v;
        }
    __syncthreads();

    // ----- cross-wave max, mean over q -----
    if (tid < 32) {
        float mx = wm[0][tid];
#pragma unroll
        for (int ww = 1; ww < 8; ++ww) mx = fmaxf(mx, wm[ww][tid]);
        mx += __shfl_xor(mx, 1); mx += __shfl_xor(mx, 2);
        mx += __shfl_xor(mx, 4); mx += __shfl_xor(mx, 8);
        mx += __shfl_xor(mx, 16);
        if (tid == 0) out[bd] = mx * (1.f / 32.f);
    }
}

extern "C" void kernel_launch(void* const* d_in, const int* in_sizes, int n_in,
                              void* d_out, int out_size, void* d_ws, size_t ws_size,
                              hipStream_t stream) {
    const float* q_hidden = (const float*)d_in[0];
    const float* d_hidden = (const float*)d_in[1];
    const int*   d_ids    = (const int*)d_in[2];
    const int*   skiplist = (const int*)d_in[3];
    const float* W        = (const float*)d_in[4];
    float* out = (float*)d_out;

    u16* Wb2 = (u16*)d_ws;                        // 128*768 bf16 = 192 KB (fragment layout)
    u16* Qb  = (u16*)((char*)d_ws + 256 * 1024);  // 64*32*128 bf16 = 512 KB

    wconv<<<192, 256, 0, stream>>>(W, (u32*)Wb2);
    qproj<<<64, 256, 0, stream>>>(q_hidden, Wb2, Qb);
    dscore<<<BD, 512, 0, stream>>>(d_hidden, d_ids, skiplist, Wb2, Qb, out);
}

// Round 3
// 175.621 us; speedup vs baseline: 1.0967x; 1.0967x over previous
//
#include <hip/hip_runtime.h>
#include <stdint.h>

typedef float  f32x4 __attribute__((ext_vector_type(4)));
typedef short  s16x8 __attribute__((ext_vector_type(8)));
typedef unsigned int u32;
typedef unsigned short u16;
typedef unsigned int u32x4 __attribute__((ext_vector_type(4)));

#define HID 768
#define OUTF 128
#define LQ 32
#define LD 256
#define BD 512

// pack two f32 -> two bf16 (round-to-nearest, ties away): 2 adds + 1 v_perm
__device__ __forceinline__ u32 pk_rna(float lo, float hi) {
    u32 a = __builtin_bit_cast(u32, lo) + 0x8000u;
    u32 b = __builtin_bit_cast(u32, hi) + 0x8000u;
    return __builtin_amdgcn_perm(b, a, 0x07060302u);  // {b.hi16, a.hi16}
}
__device__ __forceinline__ s16x8 cvt8(f32x4 lo, f32x4 hi) {
    u32x4 p;
    p[0] = pk_rna(lo[0], lo[1]);
    p[1] = pk_rna(lo[2], lo[3]);
    p[2] = pk_rna(hi[0], hi[1]);
    p[3] = pk_rna(hi[2], hi[3]);
    return __builtin_bit_cast(s16x8, p);
}
__device__ __forceinline__ u16 f2bf(float x) {
    return (u16)((__builtin_bit_cast(u32, x) + 0x8000u) >> 16);
}

// ---------------- kernel 0: W f32 -> bf16, lane-contiguous MFMA fragment layout ----
// Wb3 u16 index: ((kk*8 + cf)*64 + lane)*8 + j  <=>  W[f = cf*16 + (lane&15)][k = kk*32 + (lane>>4)*8 + j]
// So one wave's B-fragment load for (kk,cf) is 64 lanes x 16 B = 1 KB contiguous.
__global__ __launch_bounds__(256) void wconv(const float* __restrict__ W,
                                             u32* __restrict__ Wb3d) {
    int t = blockIdx.x * 256 + threadIdx.x;   // dword index 0..49151
    int j2   = t & 3;
    int lane = (t >> 2) & 63;
    int cf   = (t >> 8) & 7;
    int kk   = t >> 11;                       // 0..23
    int l15 = lane & 15, g4 = lane >> 4;
    int f = cf * 16 + l15;
    int k = kk * 32 + g4 * 8 + j2 * 2;
    const float* src = W + (size_t)f * HID + k;
    Wb3d[t] = pk_rna(src[0], src[1]);
}

// ---------------- kernel 1: Q projection + L2 norm -> bf16 ----------------
// grid = 64, block = 256 (4 waves; wave w owns cols [32w,32w+32) => cf = 2w, 2w+1)
__global__ __launch_bounds__(256) void qproj(const float* __restrict__ qh,
                                             const u16* __restrict__ Wb3,
                                             u16* __restrict__ Qb) {
    const int b = blockIdx.x;
    const int tid = threadIdx.x;
    const int w = tid >> 6, lane = tid & 63, g = lane >> 4, l15 = lane & 15;

    f32x4 acc[2][2] = {};
    const float* A0 = qh + ((size_t)b * LQ + l15) * HID + g * 8;
    const float* A1 = A0 + 16 * HID;
    const u16* Bp = Wb3 + w * 1024 + lane * 8;   // cf0 = 2w

    for (int kk = 0; kk < 24; ++kk) {
        f32x4 x0 = *(const f32x4*)A0;
        f32x4 x1 = *(const f32x4*)(A0 + 4);
        f32x4 y0 = *(const f32x4*)A1;
        f32x4 y1 = *(const f32x4*)(A1 + 4);
        s16x8 b0 = *(const s16x8*)(Bp);
        s16x8 b1 = *(const s16x8*)(Bp + 512);
        s16x8 a0 = cvt8(x0, x1);
        s16x8 a1 = cvt8(y0, y1);
        acc[0][0] = __builtin_amdgcn_mfma_f32_16x16x32_bf16(a0, b0, acc[0][0], 0, 0, 0);
        acc[0][1] = __builtin_amdgcn_mfma_f32_16x16x32_bf16(a0, b1, acc[0][1], 0, 0, 0);
        acc[1][0] = __builtin_amdgcn_mfma_f32_16x16x32_bf16(a1, b0, acc[1][0], 0, 0, 0);
        acc[1][1] = __builtin_amdgcn_mfma_f32_16x16x32_bf16(a1, b1, acc[1][1], 0, 0, 0);
        A0 += 32; A1 += 32; Bp += 4096;
    }

    __shared__ float part[4][32];
    __shared__ float invl[32];
#pragma unroll
    for (int rf = 0; rf < 2; ++rf)
#pragma unroll
        for (int reg = 0; reg < 4; ++reg) {
            float ss = acc[rf][0][reg] * acc[rf][0][reg] + acc[rf][1][reg] * acc[rf][1][reg];
            ss += __shfl_xor(ss, 1); ss += __shfl_xor(ss, 2);
            ss += __shfl_xor(ss, 4); ss += __shfl_xor(ss, 8);
            if (l15 == 0) part[w][rf * 16 + g * 4 + reg] = ss;
        }
    __syncthreads();
    if (tid < 32) {
        float ss = part[0][tid] + part[1][tid] + part[2][tid] + part[3][tid];
        invl[tid] = 1.f / fmaxf(sqrtf(ss), 1e-12f);
    }
    __syncthreads();
#pragma unroll
    for (int rf = 0; rf < 2; ++rf)
#pragma unroll
        for (int cf = 0; cf < 2; ++cf)
#pragma unroll
            for (int reg = 0; reg < 4; ++reg) {
                int q = rf * 16 + g * 4 + reg;
                int f = w * 32 + cf * 16 + l15;
                Qb[(size_t)b * LQ * OUTF + q * OUTF + f] = f2bf(acc[rf][cf][reg] * invl[q]);
            }
}

// ---------------- kernel 2: D projection + norm + mask + MaxSim (burst-staged) ------
// grid = 512 (one doc), block = 512 (8 waves). 8 row-sets of 32 rows; K split in 4
// chunks of 192 f32 (768 B bursts). 2-phase pipeline: stage s+1 while computing s.
// Wave (mr = w>>2, mc = w&3) owns 16x32 output tile of the row-set.
__global__ __launch_bounds__(512, 4) void dscore(const float* __restrict__ dh,
                                                 const int* __restrict__ ids,
                                                 const int* __restrict__ skiplist,
                                                 const u16* __restrict__ Wb3,
                                                 const u16* __restrict__ Qb,
                                                 float* __restrict__ out) {
    const int bd = blockIdx.x;
    const int tid = threadIdx.x;
    const int w = tid >> 6, lane = tid & 63, g4 = lane >> 4, l15 = lane & 15;
    const int mr = w >> 2, mc = w & 3;
    const int xr = (l15 & 7) << 4;

    __shared__ float stg[2][6144];    // 2 x 24 KB: [32 rows][192 f32], 16B-XOR swizzled
    __shared__ u16   simb[4096];      // 8 KB: frag-layout normalized D (32 rows x 128)
    __shared__ float nrmP[128];       // [mc][32 rows]
    __shared__ float invb[32];
    __shared__ int   ms[LD];
    __shared__ int   sk[64];

    const float* dh_doc = dh + (size_t)bd * LD * HID;
    const u16* Qbb = Qb + (size_t)(bd >> 3) * LQ * OUTF;

    // ----- mask -----
    if (tid < 64) sk[tid] = skiplist[tid];
    __syncthreads();
    if (tid < LD) {
        int id = ids[(size_t)bd * LD + tid];
        int keep = (id != 0);
#pragma unroll
        for (int j = 0; j < 64; ++j) keep &= (id != sk[j]);
        ms[tid] = keep;
    }

    // ----- prologue: stage s = 0 (row-set 0, k-chunk 0) -----
#pragma unroll
    for (int t = 0; t < 3; ++t) {
        int u = (w * 3 + t) * 64 + lane;          // 16B-block index 0..1535
        int row = u / 48;
        int in16 = u - row * 48;
        int innerB = (in16 << 4) ^ ((row & 7) << 4);
        f32x4 v = *(const f32x4*)(dh_doc + (size_t)row * HID + (innerB >> 2));
        *(f32x4*)&stg[0][(w * 3 + t) * 256 + lane * 4] = v;
    }
    __syncthreads();

    float rmax[2][4];
#pragma unroll
    for (int qf = 0; qf < 2; ++qf)
#pragma unroll
        for (int r = 0; r < 4; ++r) rmax[qf][r] = -INFINITY;

    f32x4 acc0 = {}, acc1 = {};

    for (int s = 0; s < 32; ++s) {
        const int cur = s & 1;
        const int kc = s & 3;
        const int r0 = (s >> 2) * 32;

        // --- issue B fragments for this chunk (oldest in vm queue) ---
        const u16* Bp = Wb3 + kc * 24576 + mc * 1024 + lane * 8;
        s16x8 bf0[6], bf1[6];
#pragma unroll
        for (int kk = 0; kk < 6; ++kk) {
            bf0[kk] = *(const s16x8*)(Bp + kk * 4096);
            bf1[kk] = *(const s16x8*)(Bp + kk * 4096 + 512);
        }
        __builtin_amdgcn_sched_barrier(0);

        // --- issue next-chunk stage loads (newest; land during compute) ---
        f32x4 sreg[3];
        if (s < 31) {
            int s1 = s + 1;
            int r01 = (s1 >> 2) * 32, kc1 = s1 & 3;
#pragma unroll
            for (int t = 0; t < 3; ++t) {
                int u = (w * 3 + t) * 64 + lane;
                int row = u / 48;
                int in16 = u - row * 48;
                int innerB = (in16 << 4) ^ ((row & 7) << 4);
                sreg[t] = *(const f32x4*)(dh_doc + (size_t)(r01 + row) * HID + kc1 * 192 + (innerB >> 2));
            }
            __builtin_amdgcn_sched_barrier(0);
        }

        // --- GEMM on staged chunk ---
        if (kc == 0) { acc0 = (f32x4){}; acc1 = (f32x4){}; }
        const char* Ab = (const char*)&stg[cur][0] + (mr * 16 + l15) * 768;
#pragma unroll
        for (int kk = 0; kk < 6; ++kk) {
            int lo = (kk * 128 + g4 * 32) ^ xr;
            f32x4 alo = *(const f32x4*)(Ab + lo);
            f32x4 ahi = *(const f32x4*)(Ab + (lo ^ 16));
            s16x8 a = cvt8(alo, ahi);
            acc0 = __builtin_amdgcn_mfma_f32_16x16x32_bf16(a, bf0[kk], acc0, 0, 0, 0);
            acc1 = __builtin_amdgcn_mfma_f32_16x16x32_bf16(a, bf1[kk], acc1, 0, 0, 0);
        }

        // --- row-set complete: norm + sim + masked max ---
        if (kc == 3) {
            // per-row sum of squares (this wave's 32 cols), reduce over l15
#pragma unroll
            for (int reg = 0; reg < 4; ++reg) {
                float ss = acc0[reg] * acc0[reg] + acc1[reg] * acc1[reg];
                ss += __shfl_xor(ss, 1); ss += __shfl_xor(ss, 2);
                ss += __shfl_xor(ss, 4); ss += __shfl_xor(ss, 8);
                if (l15 == 0) nrmP[mc * 32 + mr * 16 + g4 * 4 + reg] = ss;
            }
            asm volatile("s_waitcnt lgkmcnt(0)" ::: "memory");
            __builtin_amdgcn_s_barrier();
            if (tid < 32) {
                float t2 = nrmP[tid] + nrmP[32 + tid] + nrmP[64 + tid] + nrmP[96 + tid];
                invb[tid] = 1.f / fmaxf(sqrtf(t2), 1e-12f);
            }
            asm volatile("s_waitcnt lgkmcnt(0)" ::: "memory");
            __builtin_amdgcn_s_barrier();

            // write normalized bf16 D into frag-layout simb
#pragma unroll
            for (int cfl = 0; cfl < 2; ++cfl) {
                int f = mc * 32 + cfl * 16 + l15;
                int fb = f >> 3, j = f & 7;
#pragma unroll
                for (int reg = 0; reg < 4; ++reg) {
                    int lrow2 = mr * 16 + g4 * 4 + reg;
                    float v = (cfl ? acc1[reg] : acc0[reg]) * invb[lrow2];
                    simb[fb * 256 + lrow2 * 8 + j] = f2bf(v);
                }
            }
            asm volatile("s_waitcnt lgkmcnt(0)" ::: "memory");
            __builtin_amdgcn_s_barrier();
            __builtin_amdgcn_sched_barrier(0);

            // sim = Q (32 q) x D_set^T (32 rows), K = 128; every wave redundantly
            f32x4 s2[2][2] = {};
#pragma unroll
            for (int kq = 0; kq < 4; ++kq) {
                s16x8 qa0 = *(const s16x8*)(Qbb + (size_t)l15 * OUTF + kq * 32 + g4 * 8);
                s16x8 qa1 = *(const s16x8*)(Qbb + (size_t)(16 + l15) * OUTF + kq * 32 + g4 * 8);
                s16x8 d0 = *(const s16x8*)&simb[kq * 1024 + g4 * 256 + l15 * 8];
                s16x8 d1 = *(const s16x8*)&simb[kq * 1024 + g4 * 256 + 128 + l15 * 8];
                s2[0][0] = __builtin_amdgcn_mfma_f32_16x16x32_bf16(qa0, d0, s2[0][0], 0, 0, 0);
                s2[0][1] = __builtin_amdgcn_mfma_f32_16x16x32_bf16(qa0, d1, s2[0][1], 0, 0, 0);
                s2[1][0] = __builtin_amdgcn_mfma_f32_16x16x32_bf16(qa1, d0, s2[1][0], 0, 0, 0);
                s2[1][1] = __builtin_amdgcn_mfma_f32_16x16x32_bf16(qa1, d1, s2[1][1], 0, 0, 0);
            }
            int m0 = ms[r0 + l15];
            int m1 = ms[r0 + 16 + l15];
#pragma unroll
            for (int qf = 0; qf < 2; ++qf)
#pragma unroll
                for (int reg = 0; reg < 4; ++reg) {
                    rmax[qf][reg] = fmaxf(rmax[qf][reg], m0 ? s2[qf][0][reg] : -INFINITY);
                    rmax[qf][reg] = fmaxf(rmax[qf][reg], m1 ? s2[qf][1][reg] : -INFINITY);
                }
        }

        // --- land staged data, write to other buffer, sync ---
        if (s < 31) {
            asm volatile("s_waitcnt vmcnt(0)" ::: "memory");
            float* dstb = &stg[cur ^ 1][0];
#pragma unroll
            for (int t = 0; t < 3; ++t)
                *(f32x4*)&dstb[(w * 3 + t) * 256 + lane * 4] = sreg[t];
        }
        asm volatile("s_waitcnt lgkmcnt(0)" ::: "memory");
        __builtin_amdgcn_s_barrier();
        __builtin_amdgcn_sched_barrier(0);
    }

    // ----- final: max over l15 (drow classes), mean over q -----
    float ssum = 0.f;
#pragma unroll
    for (int qf = 0; qf < 2; ++qf)
#pragma unroll
        for (int reg = 0; reg < 4; ++reg) {
            float v = rmax[qf][reg];
            v = fmaxf(v, __shfl_xor(v, 1));
            v = fmaxf(v, __shfl_xor(v, 2));
            v = fmaxf(v, __shfl_xor(v, 4));
            v = fmaxf(v, __shfl_xor(v, 8));
            ssum += v;
        }
    ssum += __shfl_xor(ssum, 16);
    ssum += __shfl_xor(ssum, 32);
    if (tid == 0) out[bd] = ssum * (1.f / 32.f);
}

extern "C" void kernel_launch(void* const* d_in, const int* in_sizes, int n_in,
                              void* d_out, int out_size, void* d_ws, size_t ws_size,
                              hipStream_t stream) {
    const float* q_hidden = (const float*)d_in[0];
    const float* d_hidden = (const float*)d_in[1];
    const int*   d_ids    = (const int*)d_in[2];
    const int*   skiplist = (const int*)d_in[3];
    const float* W        = (const float*)d_in[4];
    float* out = (float*)d_out;

    u16* Wb3 = (u16*)d_ws;                        // 128*768 bf16 = 192 KB (lane-contiguous frags)
    u16* Qb  = (u16*)((char*)d_ws + 256 * 1024);  // 64*32*128 bf16 = 512 KB

    wconv<<<192, 256, 0, stream>>>(W, (u32*)Wb3);
    qproj<<<64, 256, 0, stream>>>(q_hidden, Wb3, Qb);
    dscore<<<BD, 512, 0, stream>>>(d_hidden, d_ids, skiplist, Wb3, Qb, out);
}

// Round 4
// 164.662 us; speedup vs baseline: 1.1697x; 1.0666x over previous
//
#include <hip/hip_runtime.h>
#include <stdint.h>

typedef float  f32x4 __attribute__((ext_vector_type(4)));
typedef short  s16x8 __attribute__((ext_vector_type(8)));
typedef unsigned int u32;
typedef unsigned short u16;
typedef unsigned int u32x4 __attribute__((ext_vector_type(4)));

#define HID 768
#define OUTF 128
#define LQ 32
#define LD 256
#define BD 512
#define NSLAB 16   // 256 rows / 16 rows per slab

// pack two f32 -> two bf16 (round-to-nearest, ties away): 2 adds + 1 v_perm
__device__ __forceinline__ u32 pk_rna(float lo, float hi) {
    u32 a = __builtin_bit_cast(u32, lo) + 0x8000u;
    u32 b = __builtin_bit_cast(u32, hi) + 0x8000u;
    return __builtin_amdgcn_perm(b, a, 0x07060302u);  // {b.hi16, a.hi16}
}
__device__ __forceinline__ s16x8 cvt8(f32x4 lo, f32x4 hi) {
    u32x4 p;
    p[0] = pk_rna(lo[0], lo[1]);
    p[1] = pk_rna(lo[2], lo[3]);
    p[2] = pk_rna(hi[0], hi[1]);
    p[3] = pk_rna(hi[2], hi[3]);
    return __builtin_bit_cast(s16x8, p);
}
__device__ __forceinline__ u16 f2bf(float x) {
    return (u16)((__builtin_bit_cast(u32, x) + 0x8000u) >> 16);
}

// async global->LDS, 16B per lane; lds dest = wave-uniform base + lane*16
__device__ __forceinline__ void gl2lds16(const void* g, void* l) {
    __builtin_amdgcn_global_load_lds((const __attribute__((address_space(1))) void*)g,
                                     (__attribute__((address_space(3))) void*)l, 16, 0, 0);
}

// ---------------- kernel 0: W f32 -> bf16, lane-contiguous MFMA fragment layout ----
// Wb3 u16 index: ((kk*8 + cf)*64 + lane)*8 + j  <=>  W[f = cf*16 + (lane&15)][k = kk*32 + (lane>>4)*8 + j]
__global__ __launch_bounds__(256) void wconv(const float* __restrict__ W,
                                             u32* __restrict__ Wb3d) {
    int t = blockIdx.x * 256 + threadIdx.x;   // dword index 0..49151
    int j2   = t & 3;
    int lane = (t >> 2) & 63;
    int cf   = (t >> 8) & 7;
    int kk   = t >> 11;                       // 0..23
    int l15 = lane & 15, g4 = lane >> 4;
    int f = cf * 16 + l15;
    int k = kk * 32 + g4 * 8 + j2 * 2;
    const float* src = W + (size_t)f * HID + k;
    Wb3d[t] = pk_rna(src[0], src[1]);
}

// ---------------- kernel 1: Q projection + L2 norm -> bf16 ----------------
__global__ __launch_bounds__(256) void qproj(const float* __restrict__ qh,
                                             const u16* __restrict__ Wb3,
                                             u16* __restrict__ Qb) {
    const int b = blockIdx.x;
    const int tid = threadIdx.x;
    const int w = tid >> 6, lane = tid & 63, g = lane >> 4, l15 = lane & 15;

    f32x4 acc[2][2] = {};
    const float* A0 = qh + ((size_t)b * LQ + l15) * HID + g * 8;
    const float* A1 = A0 + 16 * HID;
    const u16* Bp = Wb3 + w * 1024 + lane * 8;   // cf0 = 2w

    for (int kk = 0; kk < 24; ++kk) {
        f32x4 x0 = *(const f32x4*)A0;
        f32x4 x1 = *(const f32x4*)(A0 + 4);
        f32x4 y0 = *(const f32x4*)A1;
        f32x4 y1 = *(const f32x4*)(A1 + 4);
        s16x8 b0 = *(const s16x8*)(Bp);
        s16x8 b1 = *(const s16x8*)(Bp + 512);
        s16x8 a0 = cvt8(x0, x1);
        s16x8 a1 = cvt8(y0, y1);
        acc[0][0] = __builtin_amdgcn_mfma_f32_16x16x32_bf16(a0, b0, acc[0][0], 0, 0, 0);
        acc[0][1] = __builtin_amdgcn_mfma_f32_16x16x32_bf16(a0, b1, acc[0][1], 0, 0, 0);
        acc[1][0] = __builtin_amdgcn_mfma_f32_16x16x32_bf16(a1, b0, acc[1][0], 0, 0, 0);
        acc[1][1] = __builtin_amdgcn_mfma_f32_16x16x32_bf16(a1, b1, acc[1][1], 0, 0, 0);
        A0 += 32; A1 += 32; Bp += 4096;
    }

    __shared__ float part[4][32];
    __shared__ float invl[32];
#pragma unroll
    for (int rf = 0; rf < 2; ++rf)
#pragma unroll
        for (int reg = 0; reg < 4; ++reg) {
            float ss = acc[rf][0][reg] * acc[rf][0][reg] + acc[rf][1][reg] * acc[rf][1][reg];
            ss += __shfl_xor(ss, 1); ss += __shfl_xor(ss, 2);
            ss += __shfl_xor(ss, 4); ss += __shfl_xor(ss, 8);
            if (l15 == 0) part[w][rf * 16 + g * 4 + reg] = ss;
        }
    __syncthreads();
    if (tid < 32) {
        float ss = part[0][tid] + part[1][tid] + part[2][tid] + part[3][tid];
        invl[tid] = 1.f / fmaxf(sqrtf(ss), 1e-12f);
    }
    __syncthreads();
#pragma unroll
    for (int rf = 0; rf < 2; ++rf)
#pragma unroll
        for (int cf = 0; cf < 2; ++cf)
#pragma unroll
            for (int reg = 0; reg < 4; ++reg) {
                int q = rf * 16 + g * 4 + reg;
                int f = w * 32 + cf * 16 + l15;
                Qb[(size_t)b * LQ * OUTF + q * OUTF + f] = f2bf(acc[rf][cf][reg] * invl[q]);
            }
}

// ---------------- kernel 2: D projection + norm + mask + MaxSim -------------------
// grid = 512 (one doc), block = 512 (8 waves). Slab = 16 COMPLETE rows = 48 KB
// contiguous, staged via global_load_lds (linear dest, XOR-pre-swizzled source),
// double-buffered with counted vmcnt(6). Wave w owns output cols [16w,16w+16).
__global__ __launch_bounds__(512, 2) void dscore(const float* __restrict__ dh,
                                                 const int* __restrict__ ids,
                                                 const int* __restrict__ skiplist,
                                                 const u16* __restrict__ Wb3,
                                                 const u16* __restrict__ Qb,
                                                 float* __restrict__ out) {
    const int bd = blockIdx.x;
    const int tid = threadIdx.x;
    const int w = tid >> 6, lane = tid & 63, g4 = lane >> 4, l15 = lane & 15;

    __shared__ __align__(16) float stg[2][12288];   // 2 x 48 KB
    __shared__ __align__(16) u16   simb[2048];      // 4 KB: [16 rows][128] bf16, XOR-swizzled
    __shared__ float nrmP[8][16];
    __shared__ float invb[16];
    __shared__ int   ms[LD];
    __shared__ int   sk[64];

    const float* dh_doc = dh + (size_t)bd * LD * HID;

    // ----- issue slab 0 DMA as early as possible -----
    {
        float* dst = &stg[0][0];
#pragma unroll
        for (int t = 0; t < 6; ++t) {
            int rr = 2 * w + (t >= 3 ? 1 : 0);
            const char* g = (const char*)dh_doc +
                ((size_t)rr * 3072 + (t % 3) * 1024 + ((lane ^ (rr & 7)) << 4));
            char* l = (char*)dst + (w * 6 + t) * 1024;
            gl2lds16(g, l);
        }
    }

    // ----- B fragments (cols 16w..16w+16) and Q fragments: preload to registers -----
    s16x8 Bf[24];
#pragma unroll
    for (int kk = 0; kk < 24; ++kk)
        Bf[kk] = *(const s16x8*)(Wb3 + (size_t)(kk * 8 + w) * 512 + lane * 8);

    const u16* Qbb = Qb + (size_t)(bd >> 3) * LQ * OUTF;
    s16x8 Qf[2][4];
#pragma unroll
    for (int qf = 0; qf < 2; ++qf)
#pragma unroll
        for (int kq = 0; kq < 4; ++kq)
            Qf[qf][kq] = *(const s16x8*)(Qbb + (size_t)(qf * 16 + l15) * OUTF + kq * 32 + g4 * 8);

    // ----- mask -----
    if (tid < 64) sk[tid] = skiplist[tid];
    __syncthreads();   // sk ready (this drains vmcnt once in prologue; acceptable)
    if (tid < LD) {
        int id = ids[(size_t)bd * LD + tid];
        int keep = (id != 0);
#pragma unroll
        for (int j = 0; j < 64; ++j) keep &= (id != sk[j]);
        ms[tid] = keep;
    }

    const int xw = (l15 & 7) << 4;
    float rmax[2][4];
#pragma unroll
    for (int qf = 0; qf < 2; ++qf)
#pragma unroll
        for (int r = 0; r < 4; ++r) rmax[qf][r] = -INFINITY;

    for (int s = 0; s < NSLAB; ++s) {
        // --- issue next slab DMA (stays in flight across all barriers below) ---
        if (s < NSLAB - 1) {
            float* dst = &stg[(s + 1) & 1][0];
            const char* gbase = (const char*)dh_doc + (size_t)(s + 1) * 16 * 3072;
#pragma unroll
            for (int t = 0; t < 6; ++t) {
                int rr = 2 * w + (t >= 3 ? 1 : 0);
                const char* g = gbase + ((size_t)rr * 3072 + (t % 3) * 1024 + ((lane ^ (rr & 7)) << 4));
                char* l = (char*)dst + (w * 6 + t) * 1024;
                gl2lds16(g, l);
            }
            asm volatile("s_waitcnt vmcnt(6) lgkmcnt(0)" ::: "memory");
        } else {
            asm volatile("s_waitcnt vmcnt(0) lgkmcnt(0)" ::: "memory");
        }
        __builtin_amdgcn_s_barrier();          // slab s fully landed for all waves
        __builtin_amdgcn_sched_barrier(0);

        // --- GEMM: 16 rows x 16 cols (this wave), K = 768 ---
        const char* Ab = (const char*)&stg[s & 1][0] + l15 * 3072;
        f32x4 acc = {};
#pragma unroll
        for (int kk = 0; kk < 24; ++kk) {
            int lo = (kk * 128 + g4 * 32) ^ xw;
            f32x4 alo = *(const f32x4*)(Ab + lo);
            f32x4 ahi = *(const f32x4*)(Ab + (lo ^ 16));
            s16x8 a = cvt8(alo, ahi);
            acc = __builtin_amdgcn_mfma_f32_16x16x32_bf16(a, Bf[kk], acc, 0, 0, 0);
        }

        // --- per-row sum of squares: reduce over this wave's 16 cols, then waves ---
#pragma unroll
        for (int reg = 0; reg < 4; ++reg) {
            float ss = acc[reg] * acc[reg];
            ss += __shfl_xor(ss, 1); ss += __shfl_xor(ss, 2);
            ss += __shfl_xor(ss, 4); ss += __shfl_xor(ss, 8);
            if (l15 == 0) nrmP[w][g4 * 4 + reg] = ss;
        }
        asm volatile("s_waitcnt lgkmcnt(0)" ::: "memory");
        __builtin_amdgcn_s_barrier();
        __builtin_amdgcn_sched_barrier(0);
        if (tid < 16) {
            float t2 = 0.f;
#pragma unroll
            for (int ww = 0; ww < 8; ++ww) t2 += nrmP[ww][tid];
            invb[tid] = 1.f / fmaxf(sqrtf(t2), 1e-12f);
        }
        asm volatile("s_waitcnt lgkmcnt(0)" ::: "memory");
        __builtin_amdgcn_s_barrier();
        __builtin_amdgcn_sched_barrier(0);

        // --- write normalized bf16 D rows into swizzled simb ---
#pragma unroll
        for (int reg = 0; reg < 4; ++reg) {
            int row = g4 * 4 + reg;
            float v = acc[reg] * invb[row];
            int off = (row * 256 + (w * 16 + l15) * 2) ^ ((row & 7) << 4);
            *(u16*)((char*)simb + off) = f2bf(v);
        }
        asm volatile("s_waitcnt lgkmcnt(0)" ::: "memory");
        __builtin_amdgcn_s_barrier();
        __builtin_amdgcn_sched_barrier(0);

        // --- sim = Q (32 q) x D_slab^T (16 docs), K = 128; all waves redundant ---
        f32x4 s2[2] = {};
#pragma unroll
        for (int kq = 0; kq < 4; ++kq) {
            int doff = (l15 * 256 + kq * 64 + g4 * 16) ^ xw;
            s16x8 d = *(const s16x8*)((const char*)simb + doff);
            s2[0] = __builtin_amdgcn_mfma_f32_16x16x32_bf16(Qf[0][kq], d, s2[0], 0, 0, 0);
            s2[1] = __builtin_amdgcn_mfma_f32_16x16x32_bf16(Qf[1][kq], d, s2[1], 0, 0, 0);
        }
        int m0 = ms[s * 16 + l15];
#pragma unroll
        for (int qf = 0; qf < 2; ++qf)
#pragma unroll
            for (int reg = 0; reg < 4; ++reg)
                rmax[qf][reg] = fmaxf(rmax[qf][reg], m0 ? s2[qf][reg] : -INFINITY);
    }

    // ----- final: max over docs (l15 classes done; reduce l15), sum q, mean -----
    float ssum = 0.f;
#pragma unroll
    for (int qf = 0; qf < 2; ++qf)
#pragma unroll
        for (int reg = 0; reg < 4; ++reg) {
            float v = rmax[qf][reg];
            v = fmaxf(v, __shfl_xor(v, 1));
            v = fmaxf(v, __shfl_xor(v, 2));
            v = fmaxf(v, __shfl_xor(v, 4));
            v = fmaxf(v, __shfl_xor(v, 8));
            ssum += v;                          // q = qf*16 + g4*4 + reg
        }
    ssum += __shfl_xor(ssum, 16);
    ssum += __shfl_xor(ssum, 32);
    if (tid == 0) out[bd] = ssum * (1.f / 32.f);
}

extern "C" void kernel_launch(void* const* d_in, const int* in_sizes, int n_in,
                              void* d_out, int out_size, void* d_ws, size_t ws_size,
                              hipStream_t stream) {
    const float* q_hidden = (const float*)d_in[0];
    const float* d_hidden = (const float*)d_in[1];
    const int*   d_ids    = (const int*)d_in[2];
    const int*   skiplist = (const int*)d_in[3];
    const float* W        = (const float*)d_in[4];
    float* out = (float*)d_out;

    u16* Wb3 = (u16*)d_ws;                        // 128*768 bf16 = 192 KB (lane-contiguous frags)
    u16* Qb  = (u16*)((char*)d_ws + 256 * 1024);  // 64*32*128 bf16 = 512 KB

    wconv<<<192, 256, 0, stream>>>(W, (u32*)Wb3);
    qproj<<<64, 256, 0, stream>>>(q_hidden, Wb3, Qb);
    dscore<<<BD, 512, 0, stream>>>(d_hidden, d_ids, skiplist, Wb3, Qb, out);
}